// Round 5
// baseline (432.325 us; speedup 1.0000x reference)
//
#include <hip/hip_runtime.h>

typedef __attribute__((ext_vector_type(8))) short short8_t;
typedef __attribute__((ext_vector_type(4))) float f32x4;

#define MASK_VAL (-4294967295.0f)

__device__ __forceinline__ short f2bf(float x) {
    unsigned u;
    __builtin_memcpy(&u, &x, 4);
    u += 0x7FFFu + ((u >> 16) & 1u);   // round-to-nearest-even
    return (short)(u >> 16);
}
__device__ __forceinline__ float bf2f(short s) {
    unsigned u = ((unsigned)(unsigned short)s) << 16;
    float f;
    __builtin_memcpy(&f, &u, 4);
    return f;
}

// ---------------- prep: fold weights into d_ws (runs every call) ----------------
// ws layout (shorts):
//   0     : wkT  bf16 [64][64]  (W1b - W1c)^T   (row n, col k)
//   4096  : wdT  bf16 [64][64]  (W1d)^T
//   8192  : w2T  bf16 [32][64]  (W2)^T          (row o, col h)
//   10240 : wacT bf16 [64][64]  (W1a + W1c)^T   (row h, col i)
__global__ void prep_fold(const float* __restrict__ W1, const float* __restrict__ W2,
                          void* __restrict__ ws)
{
    short* wkT  = (short*)ws;
    short* wdT  = wkT + 4096;
    short* w2T  = wkT + 8192;
    short* wacT = wkT + 10240;
    const int tid = threadIdx.x;
    for (int idx = tid; idx < 4096; idx += 256) {
        int n = idx & 63, k = idx >> 6;
        float a = W1[idx];            // W1a[k][n]
        float bb = W1[4096 + idx];    // W1b[k][n]
        float c = W1[8192 + idx];     // W1c[k][n]
        float d = W1[12288 + idx];    // W1d[k][n]
        wkT [n * 64 + k] = f2bf(bb - c);
        wdT [n * 64 + k] = f2bf(d);
        wacT[n * 64 + k] = f2bf(a + c);
    }
    for (int idx = tid; idx < 2048; idx += 256) {
        int o = idx & 31, h = idx >> 5;
        w2T[o * 64 + h] = f2bf(W2[idx]);   // W2[h][o], idx = h*32+o
    }
}

// ---------------- main: one WAVE per batch, online softmax, no hot-path barriers ----
__global__ __launch_bounds__(256, 4) void attn_main(
    const float* __restrict__ query,    // (B,1,64)
    const float* __restrict__ keys,     // (B,200,64)
    const int*   __restrict__ keys_len, // (B,1)
    const float* __restrict__ b1,       // (64)
    const float* __restrict__ b2,       // (32)
    const float* __restrict__ W3,       // (32,1)
    const float* __restrict__ b3,       // (1)
    const void*  __restrict__ ws,
    float* __restrict__ out,            // (B,1,64)
    int B)
{
    constexpr int STR = 72;   // shorts; 144 B row stride -> 16B-aligned b128 everywhere
    const short* wkT  = (const short*)ws;
    const short* wdT  = wkT + 4096;
    const short* w2T  = wkT + 8192;
    const short* wacT = wkT + 10240;

    __shared__ short Bk[64 * STR];      // (W1b-W1c)^T   (block-common)
    __shared__ short Bd[64 * STR];      // W1d^T
    __shared__ short W2s[32 * STR];     // W2^T
    __shared__ short h1w[4][16 * STR];  // per-wave h1 tile
    __shared__ float qw[4][64];         // per-wave q
    __shared__ float cw[4][64];         // per-wave c vector
    __shared__ float sw[4][16];         // per-wave per-tile scores
    __shared__ float Ored[4][64];       // per-wave output shuffle-out
    __shared__ float b1s[64], b2s[32], w3s[32];

    const int tid  = threadIdx.x;
    const int lane = tid & 63;
    const int wid  = tid >> 6;
    const int col  = lane & 15;
    const int quad = lane >> 4;

    // ---- block-common staging (only barrier in the kernel) ----
    for (int c = tid; c < 512; c += 256) {
        int r = c >> 3, ch = (c & 7) * 8;
        *(short8_t*)&Bk[r * STR + ch] = *(const short8_t*)(wkT + r * 64 + ch);
        *(short8_t*)&Bd[r * STR + ch] = *(const short8_t*)(wdT + r * 64 + ch);
    }
    {
        int r = tid >> 3, ch = (tid & 7) * 8;
        *(short8_t*)&W2s[r * STR + ch] = *(const short8_t*)(w2T + r * 64 + ch);
    }
    if (tid < 64) b1s[tid] = b1[tid];
    if (tid < 32) { b2s[tid] = b2[tid]; w3s[tid] = W3[tid]; }
    __syncthreads();

    const int g = blockIdx.x * 4 + wid;
    if (g < B) {
        // ---- per-wave q ----
        if (lane < 16)
            ((float4*)qw[wid])[lane] = ((const float4*)(query + (size_t)g * 64))[lane];
        float4 qv[4];
        qv[0] = *(const float4*)&qw[wid][quad * 8];
        qv[1] = *(const float4*)&qw[wid][quad * 8 + 4];
        qv[2] = *(const float4*)&qw[wid][32 + quad * 8];
        qv[3] = *(const float4*)&qw[wid][32 + quad * 8 + 4];

        // ---- c = q @ (W1a+W1c) + b1 via 1-row MFMA (B-frags from global, L2-hot) ----
        short8_t aq0, aq1;
#pragma unroll
        for (int j = 0; j < 4; ++j) {
            aq0[j]     = (col == 0) ? f2bf(qv[0][j]) : (short)0;
            aq0[4 + j] = (col == 0) ? f2bf(qv[1][j]) : (short)0;
            aq1[j]     = (col == 0) ? f2bf(qv[2][j]) : (short)0;
            aq1[4 + j] = (col == 0) ? f2bf(qv[3][j]) : (short)0;
        }
#pragma unroll
        for (int nt = 0; nt < 4; ++nt) {
            f32x4 ac = {0.f, 0.f, 0.f, 0.f};
            const short* bp = wacT + (nt * 16 + col) * 64 + quad * 8;
            ac = __builtin_amdgcn_mfma_f32_16x16x32_bf16(aq0, *(const short8_t*)bp,        ac, 0, 0, 0);
            ac = __builtin_amdgcn_mfma_f32_16x16x32_bf16(aq1, *(const short8_t*)(bp + 32), ac, 0, 0, 0);
            if (quad == 0) cw[wid][nt * 16 + col] = ac[0] + b1s[nt * 16 + col];
        }
        float cadd[4];
#pragma unroll
        for (int nt = 0; nt < 4; ++nt) cadd[nt] = cw[wid][nt * 16 + col];

        const float b2c0 = b2s[col], b2c1 = b2s[16 + col];
        const float w3c0 = w3s[col], w3c1 = w3s[16 + col];
        const float b3v  = b3[0];
        const int   len  = keys_len[g];
        const float* kb  = keys + (size_t)g * 12800;
        short* hw = h1w[wid];

        float m_run = -INFINITY, l_run = 0.f;
        float Oacc[16];
#pragma unroll
        for (int i = 0; i < 16; ++i) Oacc[i] = 0.f;

#pragma unroll 1
        for (int mt = 0; mt < 13; ++mt) {
            int row = mt * 16 + col;
            row = row < 200 ? row : 199;                 // clamped tail reads (in-bounds)
            const float* kr = kb + row * 64 + quad * 8;
            float4 k0 = *(const float4*)(kr);
            float4 k1 = *(const float4*)(kr + 4);
            float4 k2 = *(const float4*)(kr + 32);
            float4 k3 = *(const float4*)(kr + 36);

            short8_t aK0, aK1, aQ0, aQ1;
            aK0[0] = f2bf(k0.x); aK0[1] = f2bf(k0.y); aK0[2] = f2bf(k0.z); aK0[3] = f2bf(k0.w);
            aK0[4] = f2bf(k1.x); aK0[5] = f2bf(k1.y); aK0[6] = f2bf(k1.z); aK0[7] = f2bf(k1.w);
            aK1[0] = f2bf(k2.x); aK1[1] = f2bf(k2.y); aK1[2] = f2bf(k2.z); aK1[3] = f2bf(k2.w);
            aK1[4] = f2bf(k3.x); aK1[5] = f2bf(k3.y); aK1[6] = f2bf(k3.z); aK1[7] = f2bf(k3.w);
            aQ0[0] = f2bf(k0.x * qv[0].x); aQ0[1] = f2bf(k0.y * qv[0].y);
            aQ0[2] = f2bf(k0.z * qv[0].z); aQ0[3] = f2bf(k0.w * qv[0].w);
            aQ0[4] = f2bf(k1.x * qv[1].x); aQ0[5] = f2bf(k1.y * qv[1].y);
            aQ0[6] = f2bf(k1.z * qv[1].z); aQ0[7] = f2bf(k1.w * qv[1].w);
            aQ1[0] = f2bf(k2.x * qv[2].x); aQ1[1] = f2bf(k2.y * qv[2].y);
            aQ1[2] = f2bf(k2.z * qv[2].z); aQ1[3] = f2bf(k2.w * qv[2].w);
            aQ1[4] = f2bf(k3.x * qv[3].x); aQ1[5] = f2bf(k3.y * qv[3].y);
            aQ1[6] = f2bf(k3.z * qv[3].z); aQ1[7] = f2bf(k3.w * qv[3].w);

            f32x4 acc[4] = {f32x4{0,0,0,0}, f32x4{0,0,0,0}, f32x4{0,0,0,0}, f32x4{0,0,0,0}};
#pragma unroll
            for (int nt = 0; nt < 4; ++nt) {
                const short* bp = &Bk[(nt * 16 + col) * STR + quad * 8];
                const short* dp = &Bd[(nt * 16 + col) * STR + quad * 8];
                acc[nt] = __builtin_amdgcn_mfma_f32_16x16x32_bf16(aK0, *(const short8_t*)bp,        acc[nt], 0, 0, 0);
                acc[nt] = __builtin_amdgcn_mfma_f32_16x16x32_bf16(aK1, *(const short8_t*)(bp + 32), acc[nt], 0, 0, 0);
                acc[nt] = __builtin_amdgcn_mfma_f32_16x16x32_bf16(aQ0, *(const short8_t*)dp,        acc[nt], 0, 0, 0);
                acc[nt] = __builtin_amdgcn_mfma_f32_16x16x32_bf16(aQ1, *(const short8_t*)(dp + 32), acc[nt], 0, 0, 0);
            }

            // relu + c -> per-wave h1 tile (intra-wave LDS, program-order safe)
#pragma unroll
            for (int nt = 0; nt < 4; ++nt) {
#pragma unroll
                for (int r = 0; r < 4; ++r)
                    hw[(quad * 4 + r) * STR + nt * 16 + col] = f2bf(fmaxf(acc[nt][r] + cadd[nt], 0.f));
            }

            // GEMM2 (K=64) + fused b2/relu/W3 -> per-row score
            f32x4 acc2[2] = {f32x4{0,0,0,0}, f32x4{0,0,0,0}};
#pragma unroll
            for (int ks = 0; ks < 2; ++ks) {
                short8_t a2 = *(const short8_t*)&hw[col * STR + ks * 32 + quad * 8];
                acc2[0] = __builtin_amdgcn_mfma_f32_16x16x32_bf16(
                    a2, *(const short8_t*)&W2s[col * STR + ks * 32 + quad * 8], acc2[0], 0, 0, 0);
                acc2[1] = __builtin_amdgcn_mfma_f32_16x16x32_bf16(
                    a2, *(const short8_t*)&W2s[(16 + col) * STR + ks * 32 + quad * 8], acc2[1], 0, 0, 0);
            }
            float sv[4];
#pragma unroll
            for (int r = 0; r < 4; ++r) {
                float v = fmaxf(acc2[0][r] + b2c0, 0.f) * w3c0
                        + fmaxf(acc2[1][r] + b2c1, 0.f) * w3c1;
                v += __shfl_xor(v, 1);
                v += __shfl_xor(v, 2);
                v += __shfl_xor(v, 4);
                v += __shfl_xor(v, 8);
                int t = mt * 16 + quad * 4 + r;
                sv[r] = (t < len) ? (v + b3v) : ((t < 200) ? MASK_VAL : -INFINITY);
            }
            if (col == 0) {
#pragma unroll
                for (int r = 0; r < 4; ++r) sw[wid][quad * 4 + r] = sv[r];
            }
            float sc = sw[wid][col];   // score for this lane's key row

            // online softmax update (wave-local)
            float tm = sc;
            tm = fmaxf(tm, __shfl_xor(tm, 1));
            tm = fmaxf(tm, __shfl_xor(tm, 2));
            tm = fmaxf(tm, __shfl_xor(tm, 4));
            tm = fmaxf(tm, __shfl_xor(tm, 8));
            float m_new = fmaxf(m_run, tm);
            float alpha = __expf(m_run - m_new);
            float p     = __expf(sc - m_new);
            float tl = p;
            tl += __shfl_xor(tl, 1);
            tl += __shfl_xor(tl, 2);
            tl += __shfl_xor(tl, 4);
            tl += __shfl_xor(tl, 8);
            l_run = l_run * alpha + tl;
            m_run = m_new;
#pragma unroll
            for (int i = 0; i < 8; ++i) {
                Oacc[i]     = Oacc[i]     * alpha + p * bf2f(aK0[i]);
                Oacc[8 + i] = Oacc[8 + i] * alpha + p * bf2f(aK1[i]);
            }
        }

        // ---- reduce over the 16 key rows per col-group, normalize, store ----
#pragma unroll
        for (int i = 0; i < 16; ++i) {
            float v = Oacc[i];
            v += __shfl_xor(v, 1);
            v += __shfl_xor(v, 2);
            v += __shfl_xor(v, 4);
            v += __shfl_xor(v, 8);
            Oacc[i] = v;
        }
        float rinv = 1.f / l_run;
        if (col == 0) {
#pragma unroll
            for (int i = 0; i < 8; ++i) {
                Ored[wid][quad * 8 + i]      = Oacc[i] * rinv;
                Ored[wid][32 + quad * 8 + i] = Oacc[8 + i] * rinv;
            }
        }
        out[(size_t)g * 64 + lane] = Ored[wid][lane];
    }
}

extern "C" void kernel_launch(void* const* d_in, const int* in_sizes, int n_in,
                              void* d_out, int out_size, void* d_ws, size_t ws_size,
                              hipStream_t stream) {
    const float* query    = (const float*)d_in[0];
    const float* keys     = (const float*)d_in[1];
    const int*   keys_len = (const int*)d_in[2];
    const float* W1       = (const float*)d_in[3];
    const float* b1       = (const float*)d_in[4];
    const float* W2       = (const float*)d_in[5];
    const float* b2       = (const float*)d_in[6];
    const float* W3       = (const float*)d_in[7];
    const float* b3       = (const float*)d_in[8];
    float* out            = (float*)d_out;

    const int B = in_sizes[1] / 12800;   // keys is (B,200,64)

    prep_fold<<<dim3(1), dim3(256), 0, stream>>>(W1, W2, d_ws);
    attn_main<<<dim3((B + 3) / 4), dim3(256), 0, stream>>>(
        query, keys, keys_len, b1, b2, W3, b3, d_ws, out, B);
}